// Round 16
// baseline (187.276 us; speedup 1.0000x reference)
//
#include <hip/hip_runtime.h>
#include <hip/hip_bf16.h>

#define D 128
#define NH 256
#define BM 64
#define E_TOTAL 320000
#define NNODES 10000

typedef __attribute__((ext_vector_type(8))) short bf16x8;
typedef __attribute__((ext_vector_type(4))) float f32x4;

__device__ __forceinline__ unsigned short f2b(float f) {
  unsigned int u = __builtin_bit_cast(unsigned int, f);
  u += 0x7fffu + ((u >> 16) & 1u);   // round-to-nearest-even
  return (unsigned short)(u >> 16);
}
__device__ __forceinline__ unsigned pk2(float a, float b) {
  return (unsigned)f2b(a) | ((unsigned)f2b(b) << 16);
}
__device__ __forceinline__ uint4 pack8(float4 a, float4 b) {
  uint4 r;
  r.x = pk2(a.x, a.y); r.y = pk2(a.z, a.w);
  r.z = pk2(b.x, b.y); r.w = pk2(b.z, b.w);
  return r;
}
__device__ __forceinline__ float lo2f(unsigned u) {
  return __builtin_bit_cast(float, u << 16);
}
__device__ __forceinline__ float hi2f(unsigned u) {
  return __builtin_bit_cast(float, u & 0xffff0000u);
}

// Merged prep: blocks 0..47 pack W1 (3 K=128 sections, fragment order),
// blocks 48..63 pack W2, block 64 computes cvec.
__global__ void prep_kernel(const float* __restrict__ W1,
                            const float* __restrict__ W2,
                            const float* __restrict__ b1,
                            const float* __restrict__ g,
                            ushort* __restrict__ W1pk,
                            ushort* __restrict__ W2p,
                            float* __restrict__ cvec) {
  const int b = blockIdx.x;
  const int tid = threadIdx.x;
  if (b < 48) {
    int c = b * 256 + tid;            // section s, chunk = s*4096 + nt*256 + ks*64 + l
    int s = c >> 12;
    int rem = c & 4095;
    int nt = rem >> 8;
    int rem2 = rem & 255;
    int ks = rem2 >> 6;
    int l = rem2 & 63;
    int col = nt * 16 + (l & 15);
    int k0 = s * 128 + ks * 32 + (l >> 4) * 8;
    ushort* dst = W1pk + (size_t)c * 8;
    #pragma unroll
    for (int j = 0; j < 8; ++j)
      dst[j] = f2b(W1[(size_t)(k0 + j) * NH + col]);
  } else if (b < 64) {
    int c = (b - 48) * 256 + tid;     // chunk = nt2*8 + ks
    int nt2 = c / (8 * 64);
    int rem = c % (8 * 64);
    int ks = rem >> 6;
    int l = rem & 63;
    int col = nt2 * 16 + (l & 15);
    int k0 = ks * 32 + (l >> 4) * 8;
    ushort* dst = W2p + (size_t)c * 8;
    #pragma unroll
    for (int j = 0; j < 8; ++j)
      dst[j] = f2b(W2[(size_t)(k0 + j) * D + col]);
  } else {
    int n = tid;  // 256
    float acc = b1[n];
    for (int k = 0; k < D; ++k)
      acc += g[k] * W1[(size_t)(384 + k) * NH + n];
    cvec[n] = acc;
  }
}

// Per-node partials: tbl[n][h] = nodes[n] @ W1[role*128+128 : ...][h]
// role 0 (recv) additionally folds in cvec. Swapped-orientation MFMA, K=128.
__global__ __launch_bounds__(512, 4) void nodeh_kernel(
    const float* __restrict__ nodes,
    const ushort* __restrict__ W1pk,
    const float* __restrict__ cvec,
    ushort* __restrict__ tblR,
    ushort* __restrict__ tblS) {
  __shared__ char Xn[BM * 256];
  const int role = blockIdx.y;
  ushort* __restrict__ tbl = role ? tblS : tblR;
  const int nb = blockIdx.x * BM;
  const int tid = threadIdx.x;

  {
    int row = tid >> 4;
    int cc = (tid & 15) * 16;
    #pragma unroll
    for (int q = 0; q < 2; ++q) {
      int r = row + q * 32;
      int rg = nb + r; if (rg >= NNODES) rg = NNODES - 1;
      const float* np = nodes + (size_t)rg * D + (tid & 15) * 8;
      float4 u0 = *(const float4*)np;
      float4 u1 = *(const float4*)(np + 4);
      *(uint4*)(Xn + r * 256 + (cc ^ ((r & 7) << 4))) = pack8(u0, u1);
    }
  }
  __syncthreads();

  const int lane = tid & 63;
  const int wave = tid >> 6;
  const int lr = lane & 15;
  const int kg = lane >> 4;

  const ushort* wb = W1pk + (size_t)(1 + role) * 32768
                   + (size_t)(wave * 2) * 2048 + lane * 8;
  f32x4 acc[2][4] = {};
  bf16x8 aw[2][2];
  #pragma unroll
  for (int ht = 0; ht < 2; ++ht)
    aw[0][ht] = *(const bf16x8*)(wb + ht * 2048);

  #pragma unroll
  for (int ks = 0; ks < 4; ++ks) {
    const int cur = ks & 1, nxt = cur ^ 1;
    if (ks < 3) {
      #pragma unroll
      for (int ht = 0; ht < 2; ++ht)
        aw[nxt][ht] = *(const bf16x8*)(wb + ht * 2048 + (ks + 1) * 512);
    }
    const int k0 = ks * 32 + kg * 8;
    bf16x8 xb[4];
    #pragma unroll
    for (int et = 0; et < 4; ++et) {
      int row = et * 16 + lr;
      xb[et] = *(const bf16x8*)(Xn + row * 256 + ((k0 * 2) ^ ((row & 7) << 4)));
    }
    #pragma unroll
    for (int ht = 0; ht < 2; ++ht)
      #pragma unroll
      for (int et = 0; et < 4; ++et)
        acc[ht][et] = __builtin_amdgcn_mfma_f32_16x16x32_bf16(aw[cur][ht], xb[et], acc[ht][et], 0, 0, 0);
  }

  #pragma unroll
  for (int ht = 0; ht < 2; ++ht) {
    int h0 = wave * 32 + ht * 16 + kg * 4;
    float4 cvq = {0.f, 0.f, 0.f, 0.f};
    if (role == 0) cvq = *(const float4*)(cvec + h0);
    #pragma unroll
    for (int et = 0; et < 4; ++et) {
      int n = nb + et * 16 + lr;
      if (n < NNODES) {
        uint2 pk;
        pk.x = pk2(acc[ht][et][0] + cvq.x, acc[ht][et][1] + cvq.y);
        pk.y = pk2(acc[ht][et][2] + cvq.z, acc[ht][et][3] + cvq.w);
        *(uint2*)(tbl + (size_t)n * NH + h0) = pk;
      }
    }
  }
}

// Fused edge kernel, register-gather variant:
//   H = relu(edges@W1a + tblR'[recv] + tblS[send]);  out = H@W2 + b2
// Table values gathered STRAIGHT INTO REGISTERS (lane-private uint2 per
// (role,ht,et)), issued right after the Xs barrier, AFTER preloading all
// GEMM1 weight frags (vmcnt is FIFO: weights are oldest -> GEMM1's reg+LDS
// loop never waits on the gathers; epilogue-1 is their first use).
__global__ __launch_bounds__(512, 4) void fused_kernel(
    const float* __restrict__ edges,
    const int* __restrict__ receivers,
    const int* __restrict__ senders,
    const ushort* __restrict__ W1pk,   // section 0 = edges K=128
    const ushort* __restrict__ tblR,   // includes cvec
    const ushort* __restrict__ tblS,
    const ushort* __restrict__ W2p,
    const float* __restrict__ b2,
    float* __restrict__ out) {
  __shared__ char Xs[BM * 256];   // edges bf16, swz byte ^= (row&7)<<4
  __shared__ char Hp[BM * 512];   // H bf16, same swizzle

  const int ebase = blockIdx.x * BM;
  const int tid = threadIdx.x;
  const int lane = tid & 63;
  const int wave = tid >> 6;
  const int lr = lane & 15;
  const int kg = lane >> 4;

  // ---- gather indices for this lane's epilogue edges (e = et*16 + lr)
  int idxR[4], idxS[4];
  #pragma unroll
  for (int et = 0; et < 4; ++et) {
    idxR[et] = receivers[ebase + et * 16 + lr];
    idxS[et] = senders[ebase + et * 16 + lr];
  }

  // ---- edge loads + pack -> Xs
  const int erow = tid >> 4;
  const int ecc = (tid & 15) * 16;
  {
    const float* ep0 = edges + (size_t)(ebase + erow) * D + (tid & 15) * 8;
    float4 e0 = *(const float4*)ep0;
    float4 e1 = *(const float4*)(ep0 + 4);
    const float* ep1 = edges + (size_t)(ebase + erow + 32) * D + (tid & 15) * 8;
    float4 e2 = *(const float4*)ep1;
    float4 e3 = *(const float4*)(ep1 + 4);
    *(uint4*)(Xs + erow * 256 + (ecc ^ ((erow & 7) << 4))) = pack8(e0, e1);
    int r2 = erow + 32;
    *(uint4*)(Xs + r2 * 256 + (ecc ^ ((r2 & 7) << 4))) = pack8(e2, e3);
  }
  __syncthreads();   // Xs ready (drains all prior VMEM)

  // ---- 1) preload ALL GEMM1 weight fragments (oldest post-barrier VMEM)
  const ushort* w1base = W1pk + (size_t)(wave * 2) * 2048 + lane * 8;
  bf16x8 aw[4][2];
  #pragma unroll
  for (int ks = 0; ks < 4; ++ks)
    #pragma unroll
    for (int ht = 0; ht < 2; ++ht)
      aw[ks][ht] = *(const bf16x8*)(w1base + ht * 2048 + ks * 512);

  // ---- 2) issue table gathers into registers (in flight through GEMM1)
  const int h0 = wave * 32 + kg * 4;
  uint2 gR[2][4], gS[2][4];
  #pragma unroll
  for (int ht = 0; ht < 2; ++ht)
    #pragma unroll
    for (int et = 0; et < 4; ++et) {
      gR[ht][et] = *(const uint2*)(tblR + (size_t)idxR[et] * NH + h0 + ht * 16);
      gS[ht][et] = *(const uint2*)(tblS + (size_t)idxS[et] * NH + h0 + ht * 16);
    }

  // ---- 3) GEMM1 (swapped, K=128): registers + LDS only (lgkmcnt waits)
  f32x4 acc[2][4] = {};
  #pragma unroll
  for (int ks = 0; ks < 4; ++ks) {
    const int k0 = ks * 32 + kg * 8;
    bf16x8 xb[4];
    #pragma unroll
    for (int et = 0; et < 4; ++et) {
      int row = et * 16 + lr;
      xb[et] = *(const bf16x8*)(Xs + row * 256 + ((k0 * 2) ^ ((row & 7) << 4)));
    }
    #pragma unroll
    for (int ht = 0; ht < 2; ++ht)
      #pragma unroll
      for (int et = 0; et < 4; ++et)
        acc[ht][et] = __builtin_amdgcn_mfma_f32_16x16x32_bf16(aw[ks][ht], xb[et], acc[ht][et], 0, 0, 0);
  }

  // ---- 4) epilogue 1: first gather use; H = relu(acc + R + S) -> Hp
  #pragma unroll
  for (int ht = 0; ht < 2; ++ht) {
    const int h0b = (h0 + ht * 16) * 2;
    #pragma unroll
    for (int et = 0; et < 4; ++et) {
      int e = et * 16 + lr;
      float v0 = acc[ht][et][0] + lo2f(gR[ht][et].x) + lo2f(gS[ht][et].x);
      float v1 = acc[ht][et][1] + hi2f(gR[ht][et].x) + hi2f(gS[ht][et].x);
      float v2 = acc[ht][et][2] + lo2f(gR[ht][et].y) + lo2f(gS[ht][et].y);
      float v3 = acc[ht][et][3] + hi2f(gR[ht][et].y) + hi2f(gS[ht][et].y);
      v0 = v0 > 0.f ? v0 : 0.f;
      v1 = v1 > 0.f ? v1 : 0.f;
      v2 = v2 > 0.f ? v2 : 0.f;
      v3 = v3 > 0.f ? v3 : 0.f;
      uint2 pk;
      pk.x = pk2(v0, v1);
      pk.y = pk2(v2, v3);
      *(uint2*)(Hp + e * 512 + (h0b ^ ((e & 7) << 4))) = pk;
    }
  }

  // prefetch first W2^T fragments (completes at the barrier drain)
  const int wm3 = wave >> 1;
  const int wn3 = wave & 1;
  const ushort* w2base = W2p + (size_t)(wm3 * 2) * 8 * 512 + lane * 8;
  bf16x8 aw2[2][2];
  #pragma unroll
  for (int mt = 0; mt < 2; ++mt)
    aw2[0][mt] = *(const bf16x8*)(w2base + (size_t)mt * 8 * 512);
  __syncthreads();

  // ---- 5) GEMM2 (swapped, r8-verified): out^T[32c x 32e]
  float4 ba = *(const float4*)(b2 + wm3 * 32 + kg * 4);
  float4 bb2 = *(const float4*)(b2 + wm3 * 32 + 16 + kg * 4);
  f32x4 acc2[2][2] = {};
  #pragma unroll
  for (int ks = 0; ks < 8; ++ks) {
    const int cur = ks & 1, nxt = cur ^ 1;
    if (ks < 7) {
      #pragma unroll
      for (int mt = 0; mt < 2; ++mt)
        aw2[nxt][mt] = *(const bf16x8*)(w2base + (size_t)mt * 8 * 512 + (ks + 1) * 512);
    }
    const int k0 = ks * 32 + kg * 8;
    bf16x8 hb[2];
    #pragma unroll
    for (int et2 = 0; et2 < 2; ++et2) {
      int e = wn3 * 32 + et2 * 16 + lr;
      hb[et2] = *(const bf16x8*)(Hp + e * 512 + ((k0 * 2) ^ ((e & 7) << 4)));
    }
    #pragma unroll
    for (int mt = 0; mt < 2; ++mt)
      #pragma unroll
      for (int et2 = 0; et2 < 2; ++et2)
        acc2[mt][et2] = __builtin_amdgcn_mfma_f32_16x16x32_bf16(aw2[cur][mt], hb[et2], acc2[mt][et2], 0, 0, 0);
  }

  // ---- epilogue 2: + b2, float4 stores
  #pragma unroll
  for (int mt = 0; mt < 2; ++mt) {
    const float4 bq = mt ? bb2 : ba;
    const int c0 = wm3 * 32 + mt * 16 + kg * 4;
    #pragma unroll
    for (int et2 = 0; et2 < 2; ++et2) {
      int e = wn3 * 32 + et2 * 16 + lr;
      float4 o;
      o.x = acc2[mt][et2][0] + bq.x;
      o.y = acc2[mt][et2][1] + bq.y;
      o.z = acc2[mt][et2][2] + bq.z;
      o.w = acc2[mt][et2][3] + bq.w;
      *(float4*)(out + (size_t)(ebase + e) * D + c0) = o;
    }
  }
}

extern "C" void kernel_launch(void* const* d_in, const int* in_sizes, int n_in,
                              void* d_out, int out_size, void* d_ws, size_t ws_size,
                              hipStream_t stream) {
  const float* edges     = (const float*)d_in[0];
  const float* nodes     = (const float*)d_in[1];
  const float* globals_  = (const float*)d_in[2];
  const int*   receivers = (const int*)d_in[3];
  const int*   senders   = (const int*)d_in[4];
  const float* W1        = (const float*)d_in[5];
  const float* b1        = (const float*)d_in[6];
  const float* W2        = (const float*)d_in[7];
  const float* b2        = (const float*)d_in[8];
  float* out = (float*)d_out;

  char* ws = (char*)d_ws;
  ushort* W1pk = (ushort*)ws;                       //   196,608 B
  ushort* W2p  = (ushort*)(ws + 196608);            //    65,536 B
  float*  cvec = (float*)(ws + 262144);             //     1,024 B
  ushort* tblR = (ushort*)(ws + 263168);            // 5,120,000 B
  ushort* tblS = (ushort*)(ws + 5383168);           // 5,120,000 B

  hipLaunchKernelGGL(prep_kernel, dim3(65), dim3(256), 0, stream,
                     W1, W2, b1, globals_, W1pk, W2p, cvec);
  hipLaunchKernelGGL(nodeh_kernel, dim3((NNODES + BM - 1) / BM, 2), dim3(512), 0, stream,
                     nodes, W1pk, cvec, tblR, tblS);
  hipLaunchKernelGGL(fused_kernel, dim3(E_TOTAL / BM), dim3(512), 0, stream,
                     edges, receivers, senders, W1pk, tblR, tblS, W2p, b2, out);
}

// Round 17
// 148.595 us; speedup vs baseline: 1.2603x; 1.2603x over previous
//
#include <hip/hip_runtime.h>
#include <hip/hip_bf16.h>

#define D 128
#define NH 256
#define BM 64
#define E_TOTAL 320000
#define NNODES 10000

typedef __attribute__((ext_vector_type(8))) short bf16x8;
typedef __attribute__((ext_vector_type(4))) float f32x4;

__device__ __forceinline__ unsigned short f2b(float f) {
  unsigned int u = __builtin_bit_cast(unsigned int, f);
  u += 0x7fffu + ((u >> 16) & 1u);   // round-to-nearest-even
  return (unsigned short)(u >> 16);
}
__device__ __forceinline__ unsigned pk2(float a, float b) {
  return (unsigned)f2b(a) | ((unsigned)f2b(b) << 16);
}
__device__ __forceinline__ uint4 pack8(float4 a, float4 b) {
  uint4 r;
  r.x = pk2(a.x, a.y); r.y = pk2(a.z, a.w);
  r.z = pk2(b.x, b.y); r.w = pk2(b.z, b.w);
  return r;
}
__device__ __forceinline__ float lo2f(unsigned u) {
  return __builtin_bit_cast(float, u << 16);
}
__device__ __forceinline__ float hi2f(unsigned u) {
  return __builtin_bit_cast(float, u & 0xffff0000u);
}
// async global->LDS DMA: per-lane global src, wave-uniform LDS base + lane*16
__device__ __forceinline__ void gload16(const void* g, void* l) {
  __builtin_amdgcn_global_load_lds(
      (const __attribute__((address_space(1))) void*)g,
      (__attribute__((address_space(3))) void*)l, 16, 0, 0);
}

// Merged prep: blocks 0..47 pack W1 (3 K=128 sections, fragment order),
// blocks 48..63 pack W2, block 64 computes cvec.
__global__ void prep_kernel(const float* __restrict__ W1,
                            const float* __restrict__ W2,
                            const float* __restrict__ b1,
                            const float* __restrict__ g,
                            ushort* __restrict__ W1pk,
                            ushort* __restrict__ W2p,
                            float* __restrict__ cvec) {
  const int b = blockIdx.x;
  const int tid = threadIdx.x;
  if (b < 48) {
    int c = b * 256 + tid;            // section s, chunk = s*4096 + nt*256 + ks*64 + l
    int s = c >> 12;
    int rem = c & 4095;
    int nt = rem >> 8;
    int rem2 = rem & 255;
    int ks = rem2 >> 6;
    int l = rem2 & 63;
    int col = nt * 16 + (l & 15);
    int k0 = s * 128 + ks * 32 + (l >> 4) * 8;
    ushort* dst = W1pk + (size_t)c * 8;
    #pragma unroll
    for (int j = 0; j < 8; ++j)
      dst[j] = f2b(W1[(size_t)(k0 + j) * NH + col]);
  } else if (b < 64) {
    int c = (b - 48) * 256 + tid;     // chunk = nt2*8 + ks
    int nt2 = c / (8 * 64);
    int rem = c % (8 * 64);
    int ks = rem >> 6;
    int l = rem & 63;
    int col = nt2 * 16 + (l & 15);
    int k0 = ks * 32 + (l >> 4) * 8;
    ushort* dst = W2p + (size_t)c * 8;
    #pragma unroll
    for (int j = 0; j < 8; ++j)
      dst[j] = f2b(W2[(size_t)(k0 + j) * D + col]);
  } else {
    int n = tid;  // 256
    float acc = b1[n];
    for (int k = 0; k < D; ++k)
      acc += g[k] * W1[(size_t)(384 + k) * NH + n];
    cvec[n] = acc;
  }
}

// Per-node partials: tbl[n][h] = nodes[n] @ W1[role*128+128 : ...][h]
// role 0 (recv) additionally folds in cvec. Swapped-orientation MFMA, K=128.
__global__ __launch_bounds__(512, 4) void nodeh_kernel(
    const float* __restrict__ nodes,
    const ushort* __restrict__ W1pk,
    const float* __restrict__ cvec,
    ushort* __restrict__ tblR,
    ushort* __restrict__ tblS) {
  __shared__ char Xn[BM * 256];
  const int role = blockIdx.y;
  ushort* __restrict__ tbl = role ? tblS : tblR;
  const int nb = blockIdx.x * BM;
  const int tid = threadIdx.x;

  {
    int row = tid >> 4;
    int cc = (tid & 15) * 16;
    #pragma unroll
    for (int q = 0; q < 2; ++q) {
      int r = row + q * 32;
      int rg = nb + r; if (rg >= NNODES) rg = NNODES - 1;
      const float* np = nodes + (size_t)rg * D + (tid & 15) * 8;
      float4 u0 = *(const float4*)np;
      float4 u1 = *(const float4*)(np + 4);
      *(uint4*)(Xn + r * 256 + (cc ^ ((r & 7) << 4))) = pack8(u0, u1);
    }
  }
  __syncthreads();

  const int lane = tid & 63;
  const int wave = tid >> 6;
  const int lr = lane & 15;
  const int kg = lane >> 4;

  const ushort* wb = W1pk + (size_t)(1 + role) * 32768
                   + (size_t)(wave * 2) * 2048 + lane * 8;
  f32x4 acc[2][4] = {};
  bf16x8 aw[2][2];
  #pragma unroll
  for (int ht = 0; ht < 2; ++ht)
    aw[0][ht] = *(const bf16x8*)(wb + ht * 2048);

  #pragma unroll
  for (int ks = 0; ks < 4; ++ks) {
    const int cur = ks & 1, nxt = cur ^ 1;
    if (ks < 3) {
      #pragma unroll
      for (int ht = 0; ht < 2; ++ht)
        aw[nxt][ht] = *(const bf16x8*)(wb + ht * 2048 + (ks + 1) * 512);
    }
    const int k0 = ks * 32 + kg * 8;
    bf16x8 xb[4];
    #pragma unroll
    for (int et = 0; et < 4; ++et) {
      int row = et * 16 + lr;
      xb[et] = *(const bf16x8*)(Xn + row * 256 + ((k0 * 2) ^ ((row & 7) << 4)));
    }
    #pragma unroll
    for (int ht = 0; ht < 2; ++ht)
      #pragma unroll
      for (int et = 0; et < 4; ++et)
        acc[ht][et] = __builtin_amdgcn_mfma_f32_16x16x32_bf16(aw[cur][ht], xb[et], acc[ht][et], 0, 0, 0);
  }

  #pragma unroll
  for (int ht = 0; ht < 2; ++ht) {
    int h0 = wave * 32 + ht * 16 + kg * 4;
    float4 cvq = {0.f, 0.f, 0.f, 0.f};
    if (role == 0) cvq = *(const float4*)(cvec + h0);
    #pragma unroll
    for (int et = 0; et < 4; ++et) {
      int n = nb + et * 16 + lr;
      if (n < NNODES) {
        uint2 pk;
        pk.x = pk2(acc[ht][et][0] + cvq.x, acc[ht][et][1] + cvq.y);
        pk.y = pk2(acc[ht][et][2] + cvq.z, acc[ht][et][3] + cvq.w);
        *(uint2*)(tbl + (size_t)n * NH + h0) = pk;
      }
    }
  }
}

// Fused edge kernel, async-DMA gather variant:
//   H = relu(edges@W1a + tblR'[recv] + tblS[send]);  out = H@W2 + b2
// Table rows staged via global_load_lds (coalesced 1KB/instr, zero VGPR,
// zero VALU) into Hr/Hs with the row-swizzle applied on the GLOBAL source
// address (T21/m173 pattern, validated in r13). The barrier's vmcnt(0)
// drain is where staging completes. Epilogue-1 sums Hr+Hs+acc, relu,
// writes H in place over Hr (lane-private positions); GEMM2 reads it.
__global__ __launch_bounds__(512, 4) void fused_kernel(
    const float* __restrict__ edges,
    const int* __restrict__ receivers,
    const int* __restrict__ senders,
    const ushort* __restrict__ W1pk,   // section 0 = edges K=128
    const ushort* __restrict__ tblR,   // includes cvec
    const ushort* __restrict__ tblS,
    const ushort* __restrict__ W2p,
    const float* __restrict__ b2,
    float* __restrict__ out) {
  __shared__ char Xs[BM * 256];    // edges bf16, swz byte ^= (row&7)<<4
  __shared__ char Hr[BM * 512];    // tblR rows (swz via source) -> H in place
  __shared__ char Hsb[BM * 512];   // tblS rows (swz via source)

  const int ebase = blockIdx.x * BM;
  const int tid = threadIdx.x;
  const int lane = tid & 63;
  const int wave = tid >> 6;

  // ---- async table gathers: waves 0..3 stage Hr slice, 4..7 stage Hs slice
  {
    const int wslice = wave & 3;               // 16-row slice
    const int isS = wave >> 2;
    const int* __restrict__ myarr = isS ? senders : receivers;
    const char* mytbl = (const char*)(isS ? tblS : tblR);
    char* myLds = isS ? Hsb : Hr;
    const int half = lane >> 5;                // 0/1: row within 1KB instr
    const int ch16 = (lane & 31) * 16;         // 16B chunk within row
    #pragma unroll
    for (int j = 0; j < 8; ++j) {
      int r = wslice * 16 + 2 * j + half;
      int idx = myarr[ebase + r];
      gload16(mytbl + (size_t)idx * 512 + (ch16 ^ ((r & 7) << 4)),
              myLds + (wslice * 16 + 2 * j) * 512);
    }
  }

  // ---- edge loads + pack -> Xs (reg-staged, swizzled)
  const int erow = tid >> 4;
  const int ecc = (tid & 15) * 16;
  {
    const float* ep0 = edges + (size_t)(ebase + erow) * D + (tid & 15) * 8;
    float4 e0 = *(const float4*)ep0;
    float4 e1 = *(const float4*)(ep0 + 4);
    const float* ep1 = edges + (size_t)(ebase + erow + 32) * D + (tid & 15) * 8;
    float4 e2 = *(const float4*)ep1;
    float4 e3 = *(const float4*)(ep1 + 4);
    *(uint4*)(Xs + erow * 256 + (ecc ^ ((erow & 7) << 4))) = pack8(e0, e1);
    int r2 = erow + 32;
    *(uint4*)(Xs + r2 * 256 + (ecc ^ ((r2 & 7) << 4))) = pack8(e2, e3);
  }
  __syncthreads();   // vmcnt(0): gathers landed; Xs visible

  const int lr = lane & 15;
  const int kg = lane >> 4;

  // ---- GEMM1 (swapped, K=128): H^T[32h x 64e] += W1a^T-frag * X-row-frag
  const ushort* w1base = W1pk + (size_t)(wave * 2) * 2048 + lane * 8;
  f32x4 acc[2][4] = {};
  bf16x8 aw[2][2];
  #pragma unroll
  for (int ht = 0; ht < 2; ++ht)
    aw[0][ht] = *(const bf16x8*)(w1base + ht * 2048);

  #pragma unroll
  for (int ks = 0; ks < 4; ++ks) {
    const int cur = ks & 1, nxt = cur ^ 1;
    if (ks < 3) {
      #pragma unroll
      for (int ht = 0; ht < 2; ++ht)
        aw[nxt][ht] = *(const bf16x8*)(w1base + ht * 2048 + (ks + 1) * 512);
    }
    const int k0 = ks * 32 + kg * 8;
    bf16x8 xb[4];
    #pragma unroll
    for (int et = 0; et < 4; ++et) {
      int row = et * 16 + lr;
      xb[et] = *(const bf16x8*)(Xs + row * 256 + ((k0 * 2) ^ ((row & 7) << 4)));
    }
    #pragma unroll
    for (int ht = 0; ht < 2; ++ht)
      #pragma unroll
      for (int et = 0; et < 4; ++et)
        acc[ht][et] = __builtin_amdgcn_mfma_f32_16x16x32_bf16(aw[ks & 1][ht], xb[et], acc[ht][et], 0, 0, 0);
  }

  // prefetch first W2^T fragments (complete by the next barrier)
  const int wm3 = wave >> 1;
  const int wn3 = wave & 1;
  const ushort* w2base = W2p + (size_t)(wm3 * 2) * 8 * 512 + lane * 8;
  bf16x8 aw2[2][2];
  #pragma unroll
  for (int mt = 0; mt < 2; ++mt)
    aw2[0][mt] = *(const bf16x8*)(w2base + (size_t)mt * 8 * 512);

  // ---- epilogue 1: H = relu(acc + Hr + Hs), written in place over Hr.
  // Lane-private positions (read addr == write addr) -> no cross-thread hazard.
  const int h0 = wave * 32 + kg * 4;
  #pragma unroll
  for (int ht = 0; ht < 2; ++ht) {
    const int h0b = (h0 + ht * 16) * 2;
    #pragma unroll
    for (int et = 0; et < 4; ++et) {
      int e = et * 16 + lr;
      int ad = e * 512 + (h0b ^ ((e & 7) << 4));
      uint2 gr = *(uint2*)(Hr + ad);
      uint2 gs = *(uint2*)(Hsb + ad);
      float v0 = acc[ht][et][0] + lo2f(gr.x) + lo2f(gs.x);
      float v1 = acc[ht][et][1] + hi2f(gr.x) + hi2f(gs.x);
      float v2 = acc[ht][et][2] + lo2f(gr.y) + lo2f(gs.y);
      float v3 = acc[ht][et][3] + hi2f(gr.y) + hi2f(gs.y);
      v0 = v0 > 0.f ? v0 : 0.f;
      v1 = v1 > 0.f ? v1 : 0.f;
      v2 = v2 > 0.f ? v2 : 0.f;
      v3 = v3 > 0.f ? v3 : 0.f;
      uint2 pk;
      pk.x = pk2(v0, v1);
      pk.y = pk2(v2, v3);
      *(uint2*)(Hr + ad) = pk;
    }
  }
  __syncthreads();

  // ---- GEMM2 (swapped, r8-verified): out^T[32c x 32e], A-frag = H rows (Hr)
  float4 ba = *(const float4*)(b2 + wm3 * 32 + kg * 4);
  float4 bb2 = *(const float4*)(b2 + wm3 * 32 + 16 + kg * 4);
  f32x4 acc2[2][2] = {};
  #pragma unroll
  for (int ks = 0; ks < 8; ++ks) {
    const int cur = ks & 1, nxt = cur ^ 1;
    if (ks < 7) {
      #pragma unroll
      for (int mt = 0; mt < 2; ++mt)
        aw2[nxt][mt] = *(const bf16x8*)(w2base + (size_t)mt * 8 * 512 + (ks + 1) * 512);
    }
    const int k0 = ks * 32 + kg * 8;
    bf16x8 hb[2];
    #pragma unroll
    for (int et2 = 0; et2 < 2; ++et2) {
      int e = wn3 * 32 + et2 * 16 + lr;
      hb[et2] = *(const bf16x8*)(Hr + e * 512 + ((k0 * 2) ^ ((e & 7) << 4)));
    }
    #pragma unroll
    for (int mt = 0; mt < 2; ++mt)
      #pragma unroll
      for (int et2 = 0; et2 < 2; ++et2)
        acc2[mt][et2] = __builtin_amdgcn_mfma_f32_16x16x32_bf16(aw2[cur][mt], hb[et2], acc2[mt][et2], 0, 0, 0);
  }

  // ---- epilogue 2: + b2, float4 stores (4 consecutive out cols of one edge)
  #pragma unroll
  for (int mt = 0; mt < 2; ++mt) {
    const float4 bq = mt ? bb2 : ba;
    const int c0 = wm3 * 32 + mt * 16 + kg * 4;
    #pragma unroll
    for (int et2 = 0; et2 < 2; ++et2) {
      int e = wn3 * 32 + et2 * 16 + lr;
      float4 o;
      o.x = acc2[mt][et2][0] + bq.x;
      o.y = acc2[mt][et2][1] + bq.y;
      o.z = acc2[mt][et2][2] + bq.z;
      o.w = acc2[mt][et2][3] + bq.w;
      *(float4*)(out + (size_t)(ebase + e) * D + c0) = o;
    }
  }
}

extern "C" void kernel_launch(void* const* d_in, const int* in_sizes, int n_in,
                              void* d_out, int out_size, void* d_ws, size_t ws_size,
                              hipStream_t stream) {
  const float* edges     = (const float*)d_in[0];
  const float* nodes     = (const float*)d_in[1];
  const float* globals_  = (const float*)d_in[2];
  const int*   receivers = (const int*)d_in[3];
  const int*   senders   = (const int*)d_in[4];
  const float* W1        = (const float*)d_in[5];
  const float* b1        = (const float*)d_in[6];
  const float* W2        = (const float*)d_in[7];
  const float* b2        = (const float*)d_in[8];
  float* out = (float*)d_out;

  char* ws = (char*)d_ws;
  ushort* W1pk = (ushort*)ws;                       //   196,608 B
  ushort* W2p  = (ushort*)(ws + 196608);            //    65,536 B
  float*  cvec = (float*)(ws + 262144);             //     1,024 B
  ushort* tblR = (ushort*)(ws + 263168);            // 5,120,000 B
  ushort* tblS = (ushort*)(ws + 5383168);           // 5,120,000 B

  hipLaunchKernelGGL(prep_kernel, dim3(65), dim3(256), 0, stream,
                     W1, W2, b1, globals_, W1pk, W2p, cvec);
  hipLaunchKernelGGL(nodeh_kernel, dim3((NNODES + BM - 1) / BM, 2), dim3(512), 0, stream,
                     nodes, W1pk, cvec, tblR, tblS);
  hipLaunchKernelGGL(fused_kernel, dim3(E_TOTAL / BM), dim3(512), 0, stream,
                     edges, receivers, senders, W1pk, tblR, tblS, W2p, b2, out);
}

// Round 18
// 145.299 us; speedup vs baseline: 1.2889x; 1.0227x over previous
//
#include <hip/hip_runtime.h>
#include <hip/hip_bf16.h>

#define D 128
#define NH 256
#define BM 64
#define E_TOTAL 320000
#define NNODES 10000

typedef __attribute__((ext_vector_type(8))) short bf16x8;
typedef __attribute__((ext_vector_type(4))) float f32x4;

__device__ __forceinline__ unsigned short f2b(float f) {
  unsigned int u = __builtin_bit_cast(unsigned int, f);
  u += 0x7fffu + ((u >> 16) & 1u);   // round-to-nearest-even
  return (unsigned short)(u >> 16);
}
__device__ __forceinline__ unsigned pk2(float a, float b) {
  return (unsigned)f2b(a) | ((unsigned)f2b(b) << 16);
}
__device__ __forceinline__ uint4 pack8(float4 a, float4 b) {
  uint4 r;
  r.x = pk2(a.x, a.y); r.y = pk2(a.z, a.w);
  r.z = pk2(b.x, b.y); r.w = pk2(b.z, b.w);
  return r;
}
__device__ __forceinline__ float lo2f(unsigned u) {
  return __builtin_bit_cast(float, u << 16);
}
__device__ __forceinline__ float hi2f(unsigned u) {
  return __builtin_bit_cast(float, u & 0xffff0000u);
}
// async global->LDS DMA: per-lane global src, wave-uniform LDS base + lane*16
__device__ __forceinline__ void gload16(const void* g, void* l) {
  __builtin_amdgcn_global_load_lds(
      (const __attribute__((address_space(1))) void*)g,
      (__attribute__((address_space(3))) void*)l, 16, 0, 0);
}
// barrier WITHOUT vmcnt drain (DMAs stay in flight across it)
__device__ __forceinline__ void barrier_lgkm() {
  asm volatile("s_waitcnt lgkmcnt(0)" ::: "memory");
  __builtin_amdgcn_sched_barrier(0);
  __builtin_amdgcn_s_barrier();
  __builtin_amdgcn_sched_barrier(0);
}
// barrier WITH full drain (DMA landing point)
__device__ __forceinline__ void barrier_vm0() {
  asm volatile("s_waitcnt vmcnt(0) lgkmcnt(0)" ::: "memory");
  __builtin_amdgcn_sched_barrier(0);
  __builtin_amdgcn_s_barrier();
  __builtin_amdgcn_sched_barrier(0);
}

// Merged prep + nodeh (mutually independent -> one launch):
//  b 0..23  : pack W1 (3 K=128 sections, fragment order)  [for fused]
//  b 24..31 : pack W2                                     [for fused]
//  b 32     : cvec                                        [for fused]
//  b 33..346: nodeh — tbl[n][h] = nodes[n] @ W1[role*128+128..][h]
//             (reads RAW W1 fragments: L2-hot scalar loads; no W1pk dep)
__global__ __launch_bounds__(512, 4) void prep_nodeh_kernel(
    const float* __restrict__ nodes,
    const float* __restrict__ W1,
    const float* __restrict__ W2,
    const float* __restrict__ b1,
    const float* __restrict__ g,
    ushort* __restrict__ W1pk,
    ushort* __restrict__ W2p,
    float* __restrict__ cvec,
    ushort* __restrict__ tblR,
    ushort* __restrict__ tblS) {
  __shared__ char Xn[BM * 256];
  const int b = blockIdx.x;
  const int tid = threadIdx.x;

  if (b < 24) {
    int c = b * 512 + tid;            // [s][nt][ks][l] chunks, 8 ushort each
    int s = c >> 12;
    int rem = c & 4095;
    int nt = rem >> 8;
    int rem2 = rem & 255;
    int ks = rem2 >> 6;
    int l = rem2 & 63;
    int col = nt * 16 + (l & 15);
    int k0 = s * 128 + ks * 32 + (l >> 4) * 8;
    ushort* dst = W1pk + (size_t)c * 8;
    #pragma unroll
    for (int j = 0; j < 8; ++j)
      dst[j] = f2b(W1[(size_t)(k0 + j) * NH + col]);
    return;
  }
  if (b < 32) {
    int c = (b - 24) * 512 + tid;     // chunk = nt2*8 + ks
    int nt2 = c / (8 * 64);
    int rem = c % (8 * 64);
    int ks = rem >> 6;
    int l = rem & 63;
    int col = nt2 * 16 + (l & 15);
    int k0 = ks * 32 + (l >> 4) * 8;
    ushort* dst = W2p + (size_t)c * 8;
    #pragma unroll
    for (int j = 0; j < 8; ++j)
      dst[j] = f2b(W2[(size_t)(k0 + j) * D + col]);
    return;
  }
  if (b == 32) {
    if (tid < 256) {
      int n = tid;
      float acc = b1[n];
      for (int k = 0; k < D; ++k)
        acc += g[k] * W1[(size_t)(384 + k) * NH + n];
      cvec[n] = acc;
    }
    return;
  }

  // ---- nodeh part
  const int bi = b - 33;              // 0..313
  const int role = bi >= 157;
  ushort* __restrict__ tbl = role ? tblS : tblR;
  const int nb = (bi - role * 157) * BM;

  {
    int row = tid >> 4;
    int cc = (tid & 15) * 16;
    #pragma unroll
    for (int q = 0; q < 2; ++q) {
      int r = row + q * 32;
      int rg = nb + r; if (rg >= NNODES) rg = NNODES - 1;
      const float* np = nodes + (size_t)rg * D + (tid & 15) * 8;
      float4 u0 = *(const float4*)np;
      float4 u1 = *(const float4*)(np + 4);
      *(uint4*)(Xn + r * 256 + (cc ^ ((r & 7) << 4))) = pack8(u0, u1);
    }
  }
  __syncthreads();

  const int lane = tid & 63;
  const int wave = tid >> 6;
  const int lr = lane & 15;
  const int kg = lane >> 4;
  const int col = wave * 32 + lr;     // + ht*16

  // raw W1 fragments (8 frags x 8 scalar L2-hot loads)
  bf16x8 aw[4][2];
  #pragma unroll
  for (int ks = 0; ks < 4; ++ks)
    #pragma unroll
    for (int ht = 0; ht < 2; ++ht) {
      int k0 = (1 + role) * 128 + ks * 32 + kg * 8;
      bf16x8 fr;
      #pragma unroll
      for (int j = 0; j < 8; ++j)
        fr[j] = (short)f2b(W1[(size_t)(k0 + j) * NH + col + ht * 16]);
      aw[ks][ht] = fr;
    }

  f32x4 acc[2][4] = {};
  #pragma unroll
  for (int ks = 0; ks < 4; ++ks) {
    const int k0 = ks * 32 + kg * 8;
    bf16x8 xb[4];
    #pragma unroll
    for (int et = 0; et < 4; ++et) {
      int row = et * 16 + lr;
      xb[et] = *(const bf16x8*)(Xn + row * 256 + ((k0 * 2) ^ ((row & 7) << 4)));
    }
    #pragma unroll
    for (int ht = 0; ht < 2; ++ht)
      #pragma unroll
      for (int et = 0; et < 4; ++et)
        acc[ht][et] = __builtin_amdgcn_mfma_f32_16x16x32_bf16(aw[ks][ht], xb[et], acc[ht][et], 0, 0, 0);
  }

  #pragma unroll
  for (int ht = 0; ht < 2; ++ht) {
    int h0 = wave * 32 + ht * 16 + kg * 4;
    #pragma unroll
    for (int et = 0; et < 4; ++et) {
      int n = nb + et * 16 + lr;
      if (n < NNODES) {
        uint2 pk;
        pk.x = pk2(acc[ht][et][0], acc[ht][et][1]);
        pk.y = pk2(acc[ht][et][2], acc[ht][et][3]);
        *(uint2*)(tbl + (size_t)n * NH + h0) = pk;
      }
    }
  }
}

// Fused edge kernel, split-barrier pipelined:
//   order: idx -> W1 frags (ALL, before DMAs: vmcnt FIFO) -> cvec -> edges
//          -> DMA gathers -> edge pack -> barrier A (lgkm only, DMAs fly)
//          -> GEMM1 (regs+LDS only, DMA latency hidden)
//          -> vmcnt(0)+barrier B -> epilogue-1 (acc+cvec+Hr+Hs, in place)
//          -> barrier C -> GEMM2 -> stores
__global__ __launch_bounds__(512, 4) void fused_kernel(
    const float* __restrict__ edges,
    const int* __restrict__ receivers,
    const int* __restrict__ senders,
    const ushort* __restrict__ W1pk,   // section 0 = edges K=128
    const ushort* __restrict__ tblR,
    const ushort* __restrict__ tblS,
    const float* __restrict__ cvec,
    const ushort* __restrict__ W2p,
    const float* __restrict__ b2,
    float* __restrict__ out) {
  __shared__ char Xs[BM * 256];    // edges bf16, swz byte ^= (row&7)<<4
  __shared__ char Hr[BM * 512];    // tblR rows (swz via source) -> H in place
  __shared__ char Hsb[BM * 512];   // tblS rows

  const int ebase = blockIdx.x * BM;
  const int tid = threadIdx.x;
  const int lane = tid & 63;
  const int wave = tid >> 6;
  const int lr = lane & 15;
  const int kg = lane >> 4;

  // ---- (0) gather indices (oldest vmcnt loads)
  const int wslice = wave & 3;
  const int isS = wave >> 2;
  const int* __restrict__ myarr = isS ? senders : receivers;
  const char* mytbl = (const char*)(isS ? tblS : tblR);
  char* myLds = isS ? Hsb : Hr;
  const int half = lane >> 5;
  const int ch16 = (lane & 31) * 16;
  int idx[8];
  #pragma unroll
  for (int j = 0; j < 8; ++j)
    idx[j] = myarr[ebase + wslice * 16 + 2 * j + half];

  // ---- (1) ALL GEMM1 weight fragments BEFORE the DMAs (vmcnt FIFO)
  const ushort* w1base = W1pk + (size_t)(wave * 2) * 2048 + lane * 8;
  bf16x8 aw[4][2];
  #pragma unroll
  for (int ks = 0; ks < 4; ++ks)
    #pragma unroll
    for (int ht = 0; ht < 2; ++ht)
      aw[ks][ht] = *(const bf16x8*)(w1base + ht * 2048 + ks * 512);

  // cvec quads (consumed in epilogue-1)
  float4 cva = *(const float4*)(cvec + wave * 32 + kg * 4);
  float4 cvb = *(const float4*)(cvec + wave * 32 + 16 + kg * 4);

  // ---- (2) edge loads
  const int erow = tid >> 4;
  const int ecc = (tid & 15) * 16;
  const float* ep0 = edges + (size_t)(ebase + erow) * D + (tid & 15) * 8;
  float4 e0 = *(const float4*)ep0;
  float4 e1 = *(const float4*)(ep0 + 4);
  const float* ep1 = edges + (size_t)(ebase + erow + 32) * D + (tid & 15) * 8;
  float4 e2 = *(const float4*)ep1;
  float4 e3 = *(const float4*)(ep1 + 4);

  // ---- (3) DMA gathers (latency spans GEMM1)
  #pragma unroll
  for (int j = 0; j < 8; ++j) {
    int r = wslice * 16 + 2 * j + half;
    gload16(mytbl + (size_t)idx[j] * 512 + (ch16 ^ ((r & 7) << 4)),
            myLds + (wslice * 16 + 2 * j) * 512);
  }

  // ---- (4) pack edges -> Xs (counted vmcnt: waits edges, not DMAs)
  *(uint4*)(Xs + erow * 256 + (ecc ^ ((erow & 7) << 4))) = pack8(e0, e1);
  {
    int r2 = erow + 32;
    *(uint4*)(Xs + r2 * 256 + (ecc ^ ((r2 & 7) << 4))) = pack8(e2, e3);
  }

  // ---- (A) barrier WITHOUT vmcnt drain: Xs visible, DMAs still flying
  barrier_lgkm();

  // ---- (5) GEMM1 (swapped, K=128): registers + LDS only
  f32x4 acc[2][4] = {};
  #pragma unroll
  for (int ks = 0; ks < 4; ++ks) {
    const int k0 = ks * 32 + kg * 8;
    bf16x8 xb[4];
    #pragma unroll
    for (int et = 0; et < 4; ++et) {
      int row = et * 16 + lr;
      xb[et] = *(const bf16x8*)(Xs + row * 256 + ((k0 * 2) ^ ((row & 7) << 4)));
    }
    #pragma unroll
    for (int ht = 0; ht < 2; ++ht)
      #pragma unroll
      for (int et = 0; et < 4; ++et)
        acc[ht][et] = __builtin_amdgcn_mfma_f32_16x16x32_bf16(aw[ks][ht], xb[et], acc[ht][et], 0, 0, 0);
  }

  // ---- (B) DMAs land here (hidden under GEMM1)
  barrier_vm0();

  // W2 first fragments (latency under epilogue-1)
  const int wm3 = wave >> 1;
  const int wn3 = wave & 1;
  const ushort* w2base = W2p + (size_t)(wm3 * 2) * 8 * 512 + lane * 8;
  bf16x8 aw2[2][2];
  #pragma unroll
  for (int mt = 0; mt < 2; ++mt)
    aw2[0][mt] = *(const bf16x8*)(w2base + (size_t)mt * 8 * 512);

  // ---- (6) epilogue 1: H = relu(acc + cvec + Hr + Hs), in place over Hr
  const int h0 = wave * 32 + kg * 4;
  #pragma unroll
  for (int ht = 0; ht < 2; ++ht) {
    const float4 cvq = ht ? cvb : cva;
    const int h0b = (h0 + ht * 16) * 2;
    #pragma unroll
    for (int et = 0; et < 4; ++et) {
      int e = et * 16 + lr;
      int ad = e * 512 + (h0b ^ ((e & 7) << 4));
      uint2 gr = *(uint2*)(Hr + ad);
      uint2 gs = *(uint2*)(Hsb + ad);
      float v0 = acc[ht][et][0] + cvq.x + lo2f(gr.x) + lo2f(gs.x);
      float v1 = acc[ht][et][1] + cvq.y + hi2f(gr.x) + hi2f(gs.x);
      float v2 = acc[ht][et][2] + cvq.z + lo2f(gr.y) + lo2f(gs.y);
      float v3 = acc[ht][et][3] + cvq.w + hi2f(gr.y) + hi2f(gs.y);
      v0 = v0 > 0.f ? v0 : 0.f;
      v1 = v1 > 0.f ? v1 : 0.f;
      v2 = v2 > 0.f ? v2 : 0.f;
      v3 = v3 > 0.f ? v3 : 0.f;
      uint2 pk;
      pk.x = pk2(v0, v1);
      pk.y = pk2(v2, v3);
      *(uint2*)(Hr + ad) = pk;
    }
  }

  // ---- (C) H visible to all waves
  barrier_lgkm();

  // ---- (7) GEMM2 (swapped): out^T[32c x 32e], A-frag = H rows (Hr)
  float4 ba = *(const float4*)(b2 + wm3 * 32 + kg * 4);
  float4 bb2 = *(const float4*)(b2 + wm3 * 32 + 16 + kg * 4);
  f32x4 acc2[2][2] = {};
  #pragma unroll
  for (int ks = 0; ks < 8; ++ks) {
    const int cur = ks & 1, nxt = cur ^ 1;
    if (ks < 7) {
      #pragma unroll
      for (int mt = 0; mt < 2; ++mt)
        aw2[nxt][mt] = *(const bf16x8*)(w2base + (size_t)mt * 8 * 512 + (ks + 1) * 512);
    }
    const int k0 = ks * 32 + kg * 8;
    bf16x8 hb[2];
    #pragma unroll
    for (int et2 = 0; et2 < 2; ++et2) {
      int e = wn3 * 32 + et2 * 16 + lr;
      hb[et2] = *(const bf16x8*)(Hr + e * 512 + ((k0 * 2) ^ ((e & 7) << 4)));
    }
    #pragma unroll
    for (int mt = 0; mt < 2; ++mt)
      #pragma unroll
      for (int et2 = 0; et2 < 2; ++et2)
        acc2[mt][et2] = __builtin_amdgcn_mfma_f32_16x16x32_bf16(aw2[cur][mt], hb[et2], acc2[mt][et2], 0, 0, 0);
  }

  // ---- epilogue 2: + b2, float4 stores
  #pragma unroll
  for (int mt = 0; mt < 2; ++mt) {
    const float4 bq = mt ? bb2 : ba;
    const int c0 = wm3 * 32 + mt * 16 + kg * 4;
    #pragma unroll
    for (int et2 = 0; et2 < 2; ++et2) {
      int e = wn3 * 32 + et2 * 16 + lr;
      float4 o;
      o.x = acc2[mt][et2][0] + bq.x;
      o.y = acc2[mt][et2][1] + bq.y;
      o.z = acc2[mt][et2][2] + bq.z;
      o.w = acc2[mt][et2][3] + bq.w;
      *(float4*)(out + (size_t)(ebase + e) * D + c0) = o;
    }
  }
}

extern "C" void kernel_launch(void* const* d_in, const int* in_sizes, int n_in,
                              void* d_out, int out_size, void* d_ws, size_t ws_size,
                              hipStream_t stream) {
  const float* edges     = (const float*)d_in[0];
  const float* nodes     = (const float*)d_in[1];
  const float* globals_  = (const float*)d_in[2];
  const int*   receivers = (const int*)d_in[3];
  const int*   senders   = (const int*)d_in[4];
  const float* W1        = (const float*)d_in[5];
  const float* b1        = (const float*)d_in[6];
  const float* W2        = (const float*)d_in[7];
  const float* b2        = (const float*)d_in[8];
  float* out = (float*)d_out;

  char* ws = (char*)d_ws;
  ushort* W1pk = (ushort*)ws;                       //   196,608 B
  ushort* W2p  = (ushort*)(ws + 196608);            //    65,536 B
  float*  cvec = (float*)(ws + 262144);             //     1,024 B
  ushort* tblR = (ushort*)(ws + 263168);            // 5,120,000 B
  ushort* tblS = (ushort*)(ws + 5383168);           // 5,120,000 B

  hipLaunchKernelGGL(prep_nodeh_kernel, dim3(33 + 314), dim3(512), 0, stream,
                     nodes, W1, W2, b1, globals_, W1pk, W2p, cvec, tblR, tblS);
  hipLaunchKernelGGL(fused_kernel, dim3(E_TOTAL / BM), dim3(512), 0, stream,
                     edges, receivers, senders, W1pk, tblR, tblS, cvec, W2p, b2, out);
}

// Round 19
// 142.141 us; speedup vs baseline: 1.3175x; 1.0222x over previous
//
#include <hip/hip_runtime.h>
#include <hip/hip_bf16.h>

#define D 128
#define NH 256
#define BM 64
#define E_TOTAL 320000
#define NTILES 5000
#define NBLK 256
#define NNODES 10000

typedef __attribute__((ext_vector_type(8))) short bf16x8;
typedef __attribute__((ext_vector_type(4))) float f32x4;

__device__ __forceinline__ unsigned short f2b(float f) {
  unsigned int u = __builtin_bit_cast(unsigned int, f);
  u += 0x7fffu + ((u >> 16) & 1u);   // round-to-nearest-even
  return (unsigned short)(u >> 16);
}
__device__ __forceinline__ unsigned pk2(float a, float b) {
  return (unsigned)f2b(a) | ((unsigned)f2b(b) << 16);
}
__device__ __forceinline__ uint4 pack8(float4 a, float4 b) {
  uint4 r;
  r.x = pk2(a.x, a.y); r.y = pk2(a.z, a.w);
  r.z = pk2(b.x, b.y); r.w = pk2(b.z, b.w);
  return r;
}
__device__ __forceinline__ float lo2f(unsigned u) {
  return __builtin_bit_cast(float, u << 16);
}
__device__ __forceinline__ float hi2f(unsigned u) {
  return __builtin_bit_cast(float, u & 0xffff0000u);
}
// async global->LDS DMA: per-lane global src, wave-uniform LDS base + lane*16
__device__ __forceinline__ void gload16(const void* g, void* l) {
  __builtin_amdgcn_global_load_lds(
      (const __attribute__((address_space(1))) void*)g,
      (__attribute__((address_space(3))) void*)l, 16, 0, 0);
}
// barrier WITHOUT vmcnt drain (DMAs stay in flight across it)
__device__ __forceinline__ void barrier_lgkm() {
  asm volatile("s_waitcnt lgkmcnt(0)" ::: "memory");
  __builtin_amdgcn_sched_barrier(0);
  __builtin_amdgcn_s_barrier();
  __builtin_amdgcn_sched_barrier(0);
}
// barrier WITH full drain (DMA landing point)
__device__ __forceinline__ void barrier_vm0() {
  asm volatile("s_waitcnt vmcnt(0) lgkmcnt(0)" ::: "memory");
  __builtin_amdgcn_sched_barrier(0);
  __builtin_amdgcn_s_barrier();
  __builtin_amdgcn_sched_barrier(0);
}

// Merged prep + nodeh (one launch, verified r18):
//  b 0..23  : pack W1 (3 K=128 sections, fragment order)
//  b 24..31 : pack W2
//  b 32     : cvec
//  b 33..346: nodeh — tbl[n][h] = nodes[n] @ W1[role*128+128..][h]
__global__ __launch_bounds__(512, 4) void prep_nodeh_kernel(
    const float* __restrict__ nodes,
    const float* __restrict__ W1,
    const float* __restrict__ W2,
    const float* __restrict__ b1,
    const float* __restrict__ g,
    ushort* __restrict__ W1pk,
    ushort* __restrict__ W2p,
    float* __restrict__ cvec,
    ushort* __restrict__ tblR,
    ushort* __restrict__ tblS) {
  __shared__ char Xn[BM * 256];
  const int b = blockIdx.x;
  const int tid = threadIdx.x;

  if (b < 24) {
    int c = b * 512 + tid;
    int s = c >> 12;
    int rem = c & 4095;
    int nt = rem >> 8;
    int rem2 = rem & 255;
    int ks = rem2 >> 6;
    int l = rem2 & 63;
    int col = nt * 16 + (l & 15);
    int k0 = s * 128 + ks * 32 + (l >> 4) * 8;
    ushort* dst = W1pk + (size_t)c * 8;
    #pragma unroll
    for (int j = 0; j < 8; ++j)
      dst[j] = f2b(W1[(size_t)(k0 + j) * NH + col]);
    return;
  }
  if (b < 32) {
    int c = (b - 24) * 512 + tid;
    int nt2 = c / (8 * 64);
    int rem = c % (8 * 64);
    int ks = rem >> 6;
    int l = rem & 63;
    int col = nt2 * 16 + (l & 15);
    int k0 = ks * 32 + (l >> 4) * 8;
    ushort* dst = W2p + (size_t)c * 8;
    #pragma unroll
    for (int j = 0; j < 8; ++j)
      dst[j] = f2b(W2[(size_t)(k0 + j) * D + col]);
    return;
  }
  if (b == 32) {
    if (tid < 256) {
      int n = tid;
      float acc = b1[n];
      for (int k = 0; k < D; ++k)
        acc += g[k] * W1[(size_t)(384 + k) * NH + n];
      cvec[n] = acc;
    }
    return;
  }

  const int bi = b - 33;
  const int role = bi >= 157;
  ushort* __restrict__ tbl = role ? tblS : tblR;
  const int nb = (bi - role * 157) * BM;

  {
    int row = tid >> 4;
    int cc = (tid & 15) * 16;
    #pragma unroll
    for (int q = 0; q < 2; ++q) {
      int r = row + q * 32;
      int rg = nb + r; if (rg >= NNODES) rg = NNODES - 1;
      const float* np = nodes + (size_t)rg * D + (tid & 15) * 8;
      float4 u0 = *(const float4*)np;
      float4 u1 = *(const float4*)(np + 4);
      *(uint4*)(Xn + r * 256 + (cc ^ ((r & 7) << 4))) = pack8(u0, u1);
    }
  }
  __syncthreads();

  const int lane = tid & 63;
  const int wave = tid >> 6;
  const int lr = lane & 15;
  const int kg = lane >> 4;
  const int col = wave * 32 + lr;

  bf16x8 aw[4][2];
  #pragma unroll
  for (int ks = 0; ks < 4; ++ks)
    #pragma unroll
    for (int ht = 0; ht < 2; ++ht) {
      int k0 = (1 + role) * 128 + ks * 32 + kg * 8;
      bf16x8 fr;
      #pragma unroll
      for (int j = 0; j < 8; ++j)
        fr[j] = (short)f2b(W1[(size_t)(k0 + j) * NH + col + ht * 16]);
      aw[ks][ht] = fr;
    }

  f32x4 acc[2][4] = {};
  #pragma unroll
  for (int ks = 0; ks < 4; ++ks) {
    const int k0 = ks * 32 + kg * 8;
    bf16x8 xb[4];
    #pragma unroll
    for (int et = 0; et < 4; ++et) {
      int row = et * 16 + lr;
      xb[et] = *(const bf16x8*)(Xn + row * 256 + ((k0 * 2) ^ ((row & 7) << 4)));
    }
    #pragma unroll
    for (int ht = 0; ht < 2; ++ht)
      #pragma unroll
      for (int et = 0; et < 4; ++et)
        acc[ht][et] = __builtin_amdgcn_mfma_f32_16x16x32_bf16(aw[ks][ht], xb[et], acc[ht][et], 0, 0, 0);
  }

  #pragma unroll
  for (int ht = 0; ht < 2; ++ht) {
    int h0 = wave * 32 + ht * 16 + kg * 4;
    #pragma unroll
    for (int et = 0; et < 4; ++et) {
      int n = nb + et * 16 + lr;
      if (n < NNODES) {
        uint2 pk;
        pk.x = pk2(acc[ht][et][0], acc[ht][et][1]);
        pk.y = pk2(acc[ht][et][2], acc[ht][et][3]);
        *(uint2*)(tbl + (size_t)n * NH + h0) = pk;
      }
    }
  }
}

// Persistent pipelined fused kernel (r13 structure x table formulation):
// 256 blocks (1/CU), ~20 tiles each. Per tile:
//   (1) DMA gathers(t+1) -> Hr[nxt]/Hsb[nxt]  (full tile of latency cover)
//   (2) edge loads(t+1) -> regs   (3) idx(t+2)
//   (4) GEMM1 (K=128, swapped) on Xe    (5) W2 prefetch
//   (6) epi1: H = relu(acc+cvec+Hr[cur]+Hsb[cur]) in place -> Hr[cur]
//   mid barrier (lgkm only) -> (7) GEMM2 -> (8) stores
//   (9) edges(t+1) -> Xe   (10) end barrier (vmcnt0: DMAs landed long ago)
__global__ __launch_bounds__(512) void fused_kernel(
    const float* __restrict__ edges,
    const int* __restrict__ receivers,
    const int* __restrict__ senders,
    const ushort* __restrict__ W1pk,
    const ushort* __restrict__ tblR,
    const ushort* __restrict__ tblS,
    const float* __restrict__ cvec,
    const ushort* __restrict__ W2p,
    const float* __restrict__ b2,
    float* __restrict__ out) {
  __shared__ char Xe[BM * 256];        // 16 KB, edges bf16 (single buffer)
  __shared__ char Hr[2][BM * 512];     // 64 KB, tblR gathers -> H in place
  __shared__ char Hsb[2][BM * 512];    // 64 KB, tblS gathers

  const int tid = threadIdx.x;
  const int lane = tid & 63;
  const int wave = tid >> 6;
  const int lr = lane & 15;
  const int kg = lane >> 4;

  // DMA gather geometry: waves 0..3 stage Hr 16-row slices, 4..7 stage Hsb
  const int wslice = wave & 3;
  const int isS = wave >> 2;
  const int* __restrict__ myarr = isS ? senders : receivers;
  const char* mytbl = (const char*)(isS ? tblS : tblR);
  const int half = lane >> 5;
  const int ch16 = (lane & 31) * 16;

  // edge staging geometry
  const int erow = tid >> 4;
  const int ecc = (tid & 15) * 16;

  // loop-invariant constants
  const float4 cva = *(const float4*)(cvec + wave * 32 + kg * 4);
  const float4 cvb = *(const float4*)(cvec + wave * 32 + 16 + kg * 4);
  const int wm3 = wave >> 1;
  const int wn3 = wave & 1;
  const ushort* w1base = W1pk + (size_t)(wave * 2) * 2048 + lane * 8;
  const ushort* w2base = W2p + (size_t)(wm3 * 2) * 8 * 512 + lane * 8;
  const float4 ba   = *(const float4*)(b2 + wm3 * 32 + kg * 4);
  const float4 bb2v = *(const float4*)(b2 + wm3 * 32 + 16 + kg * 4);

  int t = blockIdx.x;
  int idxn[8];

  // ---- prologue: stage tile t into buffer 0
  {
    char* myLds0 = (isS ? Hsb[0] : Hr[0]);
    #pragma unroll
    for (int j = 0; j < 8; ++j) {
      int r = wslice * 16 + 2 * j + half;
      int id0 = myarr[(size_t)t * BM + r];
      gload16(mytbl + (size_t)id0 * 512 + (ch16 ^ ((r & 7) << 4)),
              myLds0 + (wslice * 16 + 2 * j) * 512);
    }
    const float* ep0 = edges + (size_t)(t * BM + erow) * D + (tid & 15) * 8;
    float4 e0 = *(const float4*)ep0;
    float4 e1 = *(const float4*)(ep0 + 4);
    const float* ep1 = edges + (size_t)(t * BM + erow + 32) * D + (tid & 15) * 8;
    float4 e2 = *(const float4*)ep1;
    float4 e3 = *(const float4*)(ep1 + 4);
    *(uint4*)(Xe + erow * 256 + (ecc ^ ((erow & 7) << 4))) = pack8(e0, e1);
    int r2 = erow + 32;
    *(uint4*)(Xe + r2 * 256 + (ecc ^ ((r2 & 7) << 4))) = pack8(e2, e3);
    int tn0 = (t + NBLK < NTILES) ? t + NBLK : t;
    #pragma unroll
    for (int j = 0; j < 8; ++j)
      idxn[j] = myarr[(size_t)tn0 * BM + wslice * 16 + 2 * j + half];
  }
  barrier_vm0();

  int cur = 0;
  for (; t < NTILES; t += NBLK) {
    const int nxt = cur ^ 1;
    const int tn = (t + NBLK < NTILES) ? t + NBLK : t;
    const int t2 = (t + 2 * NBLK < NTILES) ? t + 2 * NBLK : tn;
    const int eb = t * BM;

    // (1) DMA gathers for tile tn -> buffers[nxt]
    {
      char* myLdsN = (isS ? Hsb[nxt] : Hr[nxt]);
      #pragma unroll
      for (int j = 0; j < 8; ++j) {
        int r = wslice * 16 + 2 * j + half;
        gload16(mytbl + (size_t)idxn[j] * 512 + (ch16 ^ ((r & 7) << 4)),
                myLdsN + (wslice * 16 + 2 * j) * 512);
      }
    }

    // (2) edge loads (tile tn) into regs
    float4 ev0, ev1, ev2, ev3;
    {
      const float* ep0 = edges + (size_t)(tn * BM + erow) * D + (tid & 15) * 8;
      ev0 = *(const float4*)ep0;
      ev1 = *(const float4*)(ep0 + 4);
      const float* ep1 = edges + (size_t)(tn * BM + erow + 32) * D + (tid & 15) * 8;
      ev2 = *(const float4*)ep1;
      ev3 = *(const float4*)(ep1 + 4);
    }

    // (3) idx prefetch for t+2*NBLK
    int idx2[8];
    #pragma unroll
    for (int j = 0; j < 8; ++j)
      idx2[j] = myarr[(size_t)t2 * BM + wslice * 16 + 2 * j + half];

    // (4) GEMM1 (swapped, K=128): A = W1pk frags (L2-streamed), B = Xe rows
    f32x4 acc[2][4] = {};
    {
      bf16x8 aw[2][2];
      #pragma unroll
      for (int ht = 0; ht < 2; ++ht)
        aw[0][ht] = *(const bf16x8*)(w1base + ht * 2048);
      #pragma unroll
      for (int ks = 0; ks < 4; ++ks) {
        if (ks < 3) {
          #pragma unroll
          for (int ht = 0; ht < 2; ++ht)
            aw[(ks + 1) & 1][ht] = *(const bf16x8*)(w1base + ht * 2048 + (ks + 1) * 512);
        }
        const int k0 = ks * 32 + kg * 8;
        bf16x8 xb[4];
        #pragma unroll
        for (int et = 0; et < 4; ++et) {
          int row = et * 16 + lr;
          xb[et] = *(const bf16x8*)(Xe + row * 256 + ((k0 * 2) ^ ((row & 7) << 4)));
        }
        #pragma unroll
        for (int ht = 0; ht < 2; ++ht)
          #pragma unroll
          for (int et = 0; et < 4; ++et)
            acc[ht][et] = __builtin_amdgcn_mfma_f32_16x16x32_bf16(aw[ks & 1][ht], xb[et], acc[ht][et], 0, 0, 0);
      }
    }

    // (5) W2 first fragments
    bf16x8 aw2[2][2];
    #pragma unroll
    for (int mt = 0; mt < 2; ++mt)
      aw2[0][mt] = *(const bf16x8*)(w2base + (size_t)mt * 8 * 512);

    // (6) epilogue 1: H = relu(acc + cvec + Hr + Hsb), in place over Hr[cur]
    const int h0 = wave * 32 + kg * 4;
    #pragma unroll
    for (int ht = 0; ht < 2; ++ht) {
      const float4 cvq = ht ? cvb : cva;
      const int h0b = (h0 + ht * 16) * 2;
      #pragma unroll
      for (int et = 0; et < 4; ++et) {
        int e = et * 16 + lr;
        int ad = e * 512 + (h0b ^ ((e & 7) << 4));
        uint2 gr = *(uint2*)(Hr[cur] + ad);
        uint2 gs = *(uint2*)(Hsb[cur] + ad);
        float v0 = acc[ht][et][0] + cvq.x + lo2f(gr.x) + lo2f(gs.x);
        float v1 = acc[ht][et][1] + cvq.y + hi2f(gr.x) + hi2f(gs.x);
        float v2 = acc[ht][et][2] + cvq.z + lo2f(gr.y) + lo2f(gs.y);
        float v3 = acc[ht][et][3] + cvq.w + hi2f(gr.y) + hi2f(gs.y);
        v0 = v0 > 0.f ? v0 : 0.f;
        v1 = v1 > 0.f ? v1 : 0.f;
        v2 = v2 > 0.f ? v2 : 0.f;
        v3 = v3 > 0.f ? v3 : 0.f;
        uint2 pk;
        pk.x = pk2(v0, v1);
        pk.y = pk2(v2, v3);
        *(uint2*)(Hr[cur] + ad) = pk;
      }
    }

    // mid barrier: H visible; DMAs for tn keep flying
    barrier_lgkm();

    // (7) GEMM2 (swapped): out^T[32c x 32e], A-frag = W2, B = H rows (Hr[cur])
    f32x4 acc2[2][2] = {};
    #pragma unroll
    for (int ks = 0; ks < 8; ++ks) {
      const int c2 = ks & 1, nx2 = c2 ^ 1;
      if (ks < 7) {
        #pragma unroll
        for (int mt = 0; mt < 2; ++mt)
          aw2[nx2][mt] = *(const bf16x8*)(w2base + (size_t)mt * 8 * 512 + (ks + 1) * 512);
      }
      const int k0 = ks * 32 + kg * 8;
      bf16x8 hb[2];
      #pragma unroll
      for (int et2 = 0; et2 < 2; ++et2) {
        int e = wn3 * 32 + et2 * 16 + lr;
        hb[et2] = *(const bf16x8*)(Hr[cur] + e * 512 + ((k0 * 2) ^ ((e & 7) << 4)));
      }
      #pragma unroll
      for (int mt = 0; mt < 2; ++mt)
        #pragma unroll
        for (int et2 = 0; et2 < 2; ++et2)
          acc2[mt][et2] = __builtin_amdgcn_mfma_f32_16x16x32_bf16(aw2[c2][mt], hb[et2], acc2[mt][et2], 0, 0, 0);
    }

    // (8) epilogue 2: + b2, float4 stores
    #pragma unroll
    for (int mt = 0; mt < 2; ++mt) {
      const float4 bq = mt ? bb2v : ba;
      const int c0 = wm3 * 32 + mt * 16 + kg * 4;
      #pragma unroll
      for (int et2 = 0; et2 < 2; ++et2) {
        int e = wn3 * 32 + et2 * 16 + lr;
        float4 o;
        o.x = acc2[mt][et2][0] + bq.x;
        o.y = acc2[mt][et2][1] + bq.y;
        o.z = acc2[mt][et2][2] + bq.z;
        o.w = acc2[mt][et2][3] + bq.w;
        *(float4*)(out + (size_t)(eb + e) * D + c0) = o;
      }
    }

    // (9) stage edges(tn) -> Xe (all waves past GEMM1: mid barrier)
    *(uint4*)(Xe + erow * 256 + (ecc ^ ((erow & 7) << 4))) = pack8(ev0, ev1);
    {
      int r2 = erow + 32;
      *(uint4*)(Xe + r2 * 256 + (ecc ^ ((r2 & 7) << 4))) = pack8(ev2, ev3);
    }

    // (10) rotate idx pipeline
    #pragma unroll
    for (int j = 0; j < 8; ++j) idxn[j] = idx2[j];

    // end barrier: DMAs(tn) had the whole tile to land
    barrier_vm0();
    cur = nxt;
  }
}

extern "C" void kernel_launch(void* const* d_in, const int* in_sizes, int n_in,
                              void* d_out, int out_size, void* d_ws, size_t ws_size,
                              hipStream_t stream) {
  const float* edges     = (const float*)d_in[0];
  const float* nodes     = (const float*)d_in[1];
  const float* globals_  = (const float*)d_in[2];
  const int*   receivers = (const int*)d_in[3];
  const int*   senders   = (const int*)d_in[4];
  const float* W1        = (const float*)d_in[5];
  const float* b1        = (const float*)d_in[6];
  const float* W2        = (const float*)d_in[7];
  const float* b2        = (const float*)d_in[8];
  float* out = (float*)d_out;

  char* ws = (char*)d_ws;
  ushort* W1pk = (ushort*)ws;                       //   196,608 B
  ushort* W2p  = (ushort*)(ws + 196608);            //    65,536 B
  float*  cvec = (float*)(ws + 262144);             //     1,024 B
  ushort* tblR = (ushort*)(ws + 263168);            // 5,120,000 B
  ushort* tblS = (ushort*)(ws + 5383168);           // 5,120,000 B

  hipLaunchKernelGGL(prep_nodeh_kernel, dim3(33 + 314), dim3(512), 0, stream,
                     nodes, W1, W2, b1, globals_, W1pk, W2p, cvec, tblR, tblS);
  hipLaunchKernelGGL(fused_kernel, dim3(NBLK), dim3(512), 0, stream,
                     edges, receivers, senders, W1pk, tblR, tblS, cvec, W2p, b2, out);
}

// Round 20
// 128.695 us; speedup vs baseline: 1.4552x; 1.1045x over previous
//
#include <hip/hip_runtime.h>
#include <hip/hip_bf16.h>

#define D 128
#define NH 256
#define K1 384
#define BM 64
#define NTILES 5000
#define NBLK 256
#define NNODES 10000

typedef __attribute__((ext_vector_type(8))) short bf16x8;
typedef __attribute__((ext_vector_type(4))) float f32x4;

__device__ __forceinline__ unsigned short f2b(float f) {
  unsigned int u = __builtin_bit_cast(unsigned int, f);
  u += 0x7fffu + ((u >> 16) & 1u);   // round-to-nearest-even
  return (unsigned short)(u >> 16);
}
__device__ __forceinline__ unsigned pk2(float a, float b) {
  return (unsigned)f2b(a) | ((unsigned)f2b(b) << 16);
}
__device__ __forceinline__ uint4 pack8(float4 a, float4 b) {
  uint4 r;
  r.x = pk2(a.x, a.y); r.y = pk2(a.z, a.w);
  r.z = pk2(b.x, b.y); r.w = pk2(b.z, b.w);
  return r;
}
// async global->LDS DMA: per-lane global src, wave-uniform LDS base + lane*16
__device__ __forceinline__ void gload16(const void* g, void* l) {
  __builtin_amdgcn_global_load_lds(
      (const __attribute__((address_space(1))) void*)g,
      (__attribute__((address_space(3))) void*)l, 16, 0, 0);
}

// Merged prep (all parts mutually independent -> ONE launch):
//  b 0..1249   : nodes fp32 -> bf16 table
//  b 1250..1297: pack W1 rows [0:384) into MFMA-fragment order
//                chunk c = nt*768 + ks*64 + l ; lane l holds
//                W1[ks*32+(l>>4)*8 + j][nt*16+(l&15)]
//  b 1298..1313: pack W2 (chunk c = nt2*512 + ks*64 + l, same frag order)
//  b 1314      : cvec[n] = b1[n] + sum_k globals[k]*W1[384+k][n]
__global__ void prep_kernel(const float* __restrict__ nodes,
                            const float* __restrict__ W1,
                            const float* __restrict__ W2,
                            const float* __restrict__ b1,
                            const float* __restrict__ g,
                            ushort* __restrict__ nodes_b,
                            ushort* __restrict__ W1p,
                            ushort* __restrict__ W2p,
                            float* __restrict__ cvec) {
  const int b = blockIdx.x;
  const int tid = threadIdx.x;
  if (b < 1250) {
    int i = (b * 256 + tid) * 4;
    float4 v = *(const float4*)(nodes + i);
    ushort4 o;
    o.x = f2b(v.x); o.y = f2b(v.y); o.z = f2b(v.z); o.w = f2b(v.w);
    *(ushort4*)(nodes_b + i) = o;
    return;
  }
  if (b < 1298) {
    int c = (b - 1250) * 256 + tid;   // 12288 chunks
    int nt = c / (12 * 64);
    int rem = c % (12 * 64);
    int ks = rem >> 6;
    int l = rem & 63;
    int col = nt * 16 + (l & 15);
    int k0 = ks * 32 + (l >> 4) * 8;
    ushort* dst = W1p + (size_t)c * 8;
    #pragma unroll
    for (int j = 0; j < 8; ++j)
      dst[j] = f2b(W1[(size_t)(k0 + j) * NH + col]);
    return;
  }
  if (b < 1314) {
    int c = (b - 1298) * 256 + tid;   // 4096 chunks
    int nt2 = c / (8 * 64);
    int rem = c % (8 * 64);
    int ks = rem >> 6;
    int l = rem & 63;
    int col = nt2 * 16 + (l & 15);
    int k0 = ks * 32 + (l >> 4) * 8;
    ushort* dst = W2p + (size_t)c * 8;
    #pragma unroll
    for (int j = 0; j < 8; ++j)
      dst[j] = f2b(W2[(size_t)(k0 + j) * D + col]);
    return;
  }
  {
    int n = tid;  // 256
    float acc = b1[n];
    for (int k = 0; k < D; ++k)
      acc += g[k] * W1[(size_t)(K1 + k) * NH + n];
    cvec[n] = acc;
  }
}

// Persistent pipelined kernel (r13 champion structure), W1 register-resident:
// 256 blocks (1/CU, forced by 128 KB LDS), ~20 tiles each.
// __launch_bounds__(512,1) -> 256 VGPR cap (r6's spill was the 128-reg cap
// from (512,2), not the idea). w1f[2][12] = 96 VGPR loaded ONCE; GEMM1 is
// pure LDS+register (no vmcnt in the K-loop). W2 streamed (depth-1 dbuf).
__global__ __launch_bounds__(512, 1) void fused_kernel(
    const float* __restrict__ edges,
    const ushort* __restrict__ nodes_b,
    const int* __restrict__ receivers,
    const int* __restrict__ senders,
    const ushort* __restrict__ W1p,    // packed fragments, 16nt x 12ks x 64lane x 8
    const float* __restrict__ cvec,    // [256]
    const ushort* __restrict__ W2p,    // packed fragments, 8nt x 8ks x 64lane x 8
    const float* __restrict__ b2,      // [128]
    float* __restrict__ out) {
  __shared__ char Xe[2][BM * 256];   // edges  : 2 x 16 KB, swz byte^((row&7)<<4)
  __shared__ char Xg[2][BM * 512];   // gathers: 2 x 32 KB, linear dest / pre-swz src
  __shared__ char Hs[BM * 512];      // hidden : 32 KB, swz

  const int tid = threadIdx.x;
  const int lane = tid & 63;
  const int wave = tid >> 6;
  const int lr = lane & 15;
  const int kg = lane >> 4;

  // ---- gather-staging geometry: wave stages Xg rows [8w, 8w+8), 4 instrs x 1024B
  const int l31 = lane & 31;
  const int myr = wave * 8 + (lane >> 5);        // row for instr j: myr + 2j
  const int gc2 = (l31 * 16) & 255;              // within-section byte (16B chunk)
  const int gsec = (l31 >= 16);                  // 0 = recv half, 1 = send half
  const int* __restrict__ myarr = gsec ? senders : receivers;

  // ---- edge-staging geometry: thread handles chunks tid, tid+512
  const int erow0 = tid >> 4;                    // rows erow0, erow0+32
  const int ecc = (tid & 15) * 16;               // dest byte in 256B row

  // ---- compute constants
  float cv[2];
  #pragma unroll
  for (int n = 0; n < 2; ++n) cv[n] = cvec[wave * 32 + n * 16 + lr];
  const float bias = b2[wave * 16 + lr];
  const ushort* w1base = W1p + (size_t)(wave * 2) * 12 * 512 + lane * 8;
  const ushort* w2base = W2p + (size_t)wave * 8 * 512 + lane * 8;

  // ---- W1 fragments resident for the whole kernel (24 x bf16x8 = 96 VGPR)
  bf16x8 w1f[2][12];
  #pragma unroll
  for (int n = 0; n < 2; ++n)
    #pragma unroll
    for (int ks = 0; ks < 12; ++ks)
      w1f[n][ks] = *(const bf16x8*)(w1base + ((size_t)n * 12 + ks) * 512);

  int t = blockIdx.x;
  int idxn[4];

  // ---- prologue: stage tile t into buffer 0; preload idx for t+NBLK
  {
    const int eb = t * BM;
    int idx0[4];
    #pragma unroll
    for (int j = 0; j < 4; ++j) idx0[j] = myarr[eb + myr + 2 * j];
    #pragma unroll
    for (int j = 0; j < 4; ++j) {
      int r = myr + 2 * j;
      gload16(nodes_b + (size_t)idx0[j] * D + ((gc2 ^ ((r & 7) << 4)) >> 1),
              &Xg[0][wave * 4096 + j * 1024]);
    }
    #pragma unroll
    for (int q = 0; q < 2; ++q) {
      int row = erow0 + q * 32;
      const float* ep = edges + (size_t)(eb + row) * D + (ecc >> 1);
      float4 u0 = *(const float4*)ep;
      float4 u1 = *(const float4*)(ep + 4);
      *(uint4*)(&Xe[0][row * 256 + (ecc ^ ((row & 7) << 4))]) = pack8(u0, u1);
    }
    const int tn0 = (t + NBLK < NTILES) ? t + NBLK : t;
    #pragma unroll
    for (int j = 0; j < 4; ++j) idxn[j] = myarr[tn0 * BM + myr + 2 * j];
    __syncthreads();   // drains gload_lds (vmcnt 0) + makes Xe visible
  }

  int cur = 0;
  for (; t < NTILES; t += NBLK) {
    const int eb = t * BM;
    const int tn = (t + NBLK < NTILES) ? t + NBLK : t;
    const int t2 = (t + 2 * NBLK < NTILES) ? t + 2 * NBLK : tn;
    const int nxt = cur ^ 1;

    // 1. async gathers (tile tn) -> Xg[nxt]  (no registers held)
    #pragma unroll
    for (int j = 0; j < 4; ++j) {
      int r = myr + 2 * j;
      gload16(nodes_b + (size_t)idxn[j] * D + ((gc2 ^ ((r & 7) << 4)) >> 1),
              &Xg[nxt][wave * 4096 + j * 1024]);
    }
    // 2. edge loads (tile tn) into regs (16 VGPR, written to LDS post-GEMM2)
    float4 ev[4];
    #pragma unroll
    for (int q = 0; q < 2; ++q) {
      int row = erow0 + q * 32;
      const float* ep = edges + (size_t)(tn * BM + row) * D + (ecc >> 1);
      ev[2 * q]     = *(const float4*)ep;
      ev[2 * q + 1] = *(const float4*)(ep + 4);
    }
    // 3. idx prefetch for t+2
    int idx2[4];
    #pragma unroll
    for (int j = 0; j < 4; ++j) idx2[j] = myarr[t2 * BM + myr + 2 * j];

    // 4. GEMM1 on buffers[cur]: [64x384] @ [384x32-per-wave],
    //    A from LDS, B from RESIDENT REGISTERS (no vmcnt in loop)
    f32x4 acc[4][2] = {};
    #pragma unroll
    for (int ks = 0; ks < 12; ++ks) {
      const int k0 = ks * 32 + kg * 8;
      bf16x8 a[4];
      #pragma unroll
      for (int m = 0; m < 4; ++m) {
        int row = m * 16 + lr;
        int swz = (row & 7) << 4;
        const char* ap;
        if (ks < 4)       ap = &Xe[cur][row * 256 + ((k0 * 2) ^ swz)];
        else if (ks < 8)  ap = &Xg[cur][row * 512 + (((k0 - 128) * 2) ^ swz)];
        else              ap = &Xg[cur][row * 512 + 256 + (((k0 - 256) * 2) ^ swz)];
        a[m] = *(const bf16x8*)ap;
      }
      #pragma unroll
      for (int m = 0; m < 4; ++m)
        #pragma unroll
        for (int n = 0; n < 2; ++n)
          acc[m][n] = __builtin_amdgcn_mfma_f32_16x16x32_bf16(a[m], w1f[n][ks], acc[m][n], 0, 0, 0);
    }

    // prefetch first W2 fragment (no Hs dependency)
    bf16x8 b2b[2];
    b2b[0] = *(const bf16x8*)w2base;

    // 5. epilogue 1: + cvec, relu -> bf16 Hs
    #pragma unroll
    for (int n = 0; n < 2; ++n) {
      int col = wave * 32 + n * 16 + lr;
      #pragma unroll
      for (int m = 0; m < 4; ++m) {
        #pragma unroll
        for (int r = 0; r < 4; ++r) {
          int row = m * 16 + kg * 4 + r;
          float v = acc[m][n][r] + cv[n];
          v = v > 0.f ? v : 0.f;
          *(ushort*)(&Hs[row * 512 + ((col * 2) ^ ((row & 7) << 4))]) = f2b(v);
        }
      }
    }

    // 6. barrier (staging for tn completes here, hidden under GEMM1)
    __syncthreads();

    // 7. GEMM2: [64x256] @ [256x16-per-wave] + stores (tile t)
    f32x4 acc2[4] = {};
    #pragma unroll
    for (int ks = 0; ks < 8; ++ks) {
      const int c2 = ks & 1, nx2 = c2 ^ 1;
      if (ks < 7)
        b2b[nx2] = *(const bf16x8*)(w2base + (ks + 1) * 512);
      const int k0 = ks * 32 + kg * 8;
      bf16x8 a2[4];
      #pragma unroll
      for (int m = 0; m < 4; ++m) {
        int row = m * 16 + lr;
        a2[m] = *(const bf16x8*)(&Hs[row * 512 + ((k0 * 2) ^ ((row & 7) << 4))]);
      }
      #pragma unroll
      for (int m = 0; m < 4; ++m)
        acc2[m] = __builtin_amdgcn_mfma_f32_16x16x32_bf16(a2[m], b2b[c2], acc2[m], 0, 0, 0);
    }
    {
      int col = wave * 16 + lr;
      #pragma unroll
      for (int m = 0; m < 4; ++m) {
        #pragma unroll
        for (int r = 0; r < 4; ++r) {
          int row = m * 16 + kg * 4 + r;
          out[(size_t)(eb + row) * D + col] = acc2[m][r] + bias;
        }
      }
    }

    // 8. convert + write staged edges -> Xe[nxt]
    #pragma unroll
    for (int q = 0; q < 2; ++q) {
      int row = erow0 + q * 32;
      *(uint4*)(&Xe[nxt][row * 256 + (ecc ^ ((row & 7) << 4))]) =
          pack8(ev[2 * q], ev[2 * q + 1]);
    }

    // 9. rotate idx pipeline
    #pragma unroll
    for (int j = 0; j < 4; ++j) idxn[j] = idx2[j];

    // 10. tile boundary
    __syncthreads();
    cur = nxt;
  }
}

extern "C" void kernel_launch(void* const* d_in, const int* in_sizes, int n_in,
                              void* d_out, int out_size, void* d_ws, size_t ws_size,
                              hipStream_t stream) {
  const float* edges     = (const float*)d_in[0];
  const float* nodes     = (const float*)d_in[1];
  const float* globals_  = (const float*)d_in[2];
  const int*   receivers = (const int*)d_in[3];
  const int*   senders   = (const int*)d_in[4];
  const float* W1        = (const float*)d_in[5];
  const float* b1        = (const float*)d_in[6];
  const float* W2        = (const float*)d_in[7];
  const float* b2        = (const float*)d_in[8];
  float* out = (float*)d_out;

  char* ws = (char*)d_ws;
  ushort* nodes_b = (ushort*)ws;                                // 2,560,000 B
  ushort* W1p     = (ushort*)(ws + 2560000);                    //   196,608 B
  ushort* W2p     = (ushort*)(ws + 2560000 + 196608);           //    65,536 B
  float*  cvec    = (float*)(ws + 2560000 + 196608 + 65536);    //     1,024 B

  hipLaunchKernelGGL(prep_kernel, dim3(1315), dim3(256), 0, stream,
                     nodes, W1, W2, b1, globals_, nodes_b, W1p, W2p, cvec);
  hipLaunchKernelGGL(fused_kernel, dim3(NBLK), dim3(512), 0, stream,
                     edges, nodes_b, receivers, senders, W1p, cvec, W2p, b2, out);
}